// Round 3
// baseline (1401.865 us; speedup 1.0000x reference)
//
#include <hip/hip_runtime.h>

// Problem: B=8, L=1024, C=384, H=6, D=64, K=2(radial), N=4(angular)
// R3 = all-VALU f32 diagnostic build (no MFMA, no shuffles in attn).
typedef unsigned int  u32;
typedef unsigned short u16;

__device__ __forceinline__ u16 f2bf(float x) {
  union { float f; u32 u; } un; un.f = x;
  u32 r = un.u + 0x7FFFu + ((un.u >> 16) & 1u);   // RNE
  return (u16)(r >> 16);
}
__device__ __forceinline__ float bflo(u32 u) {
  union { u32 u; float f; } c; c.u = u << 16; return c.f;
}
__device__ __forceinline__ float bfhi(u32 u) {
  union { u32 u; float f; } c; c.u = u & 0xFFFF0000u; return c.f;
}
__device__ __forceinline__ float b2f(u16 v) {
  union { u32 u; float f; } c; c.u = ((u32)v) << 16; return c.f;
}

// ---------------- prep: RMSNorm -> xn(bf16), convert w_in/w_out -> bf16 ----
__global__ __launch_bounds__(256) void prep_kernel(
    const float* __restrict__ x, const float* __restrict__ w_norm,
    const float* __restrict__ w_in, const float* __restrict__ w_out,
    u16* __restrict__ xn, u16* __restrict__ winb, u16* __restrict__ woutb)
{
  int blk = blockIdx.x, t = threadIdx.x;
  if (blk < 2048) {               // 8192 rows, 4 rows/block (1 per wave)
    int wv = t >> 6, lane = t & 63;
    int row = blk * 4 + wv;
    const float* xr = x + (size_t)row * 384;
    float v[6]; float ss = 0.f;
    #pragma unroll
    for (int i = 0; i < 6; i++) { v[i] = xr[lane + 64 * i]; ss += v[i] * v[i]; }
    #pragma unroll
    for (int off = 32; off > 0; off >>= 1) ss += __shfl_xor(ss, off);
    float rs = __builtin_amdgcn_rsqf(ss * (1.0f / 384.0f) + 1e-5f);
    #pragma unroll
    for (int i = 0; i < 6; i++) {
      float xv = v[i] * rs * w_norm[lane + 64 * i];
      xn[(size_t)row * 384 + lane + 64 * i] = f2bf(xv);
    }
  } else {                        // weight conversion: 442368 + 147456
    int base = (blk - 2048) * 2048 + t * 8;
    #pragma unroll
    for (int j = 0; j < 8; j++) {
      int idx = base + j;
      if (idx < 442368) winb[idx] = f2bf(w_in[idx]);
      else              woutb[idx - 442368] = f2bf(w_out[idx - 442368]);
    }
  }
}

// ---------------- VALU GEMM: out[M,.] = A[M,K]*Bw[N,K]^T + bias ------------
// 64x64 tile, BK=16, 256 threads, 4x4 per thread, f32 LDS (k-major).
template<bool OUT_F32, bool QSCALE>
__global__ __launch_bounds__(256) void gemm_valu(
    const u16* __restrict__ A, int lda,
    const u16* __restrict__ Bw, int ldb,
    const float* __restrict__ bias, void* __restrict__ outp, int ldc, int K)
{
  __shared__ __attribute__((aligned(16))) float As[16][68];
  __shared__ __attribute__((aligned(16))) float Bs[16][68];
  int t = threadIdx.x;
  int row0 = blockIdx.x * 64, col0 = blockIdx.y * 64;
  int tr = t >> 4, tc = t & 15;
  float acc[4][4];
  #pragma unroll
  for (int i = 0; i < 4; i++)
    #pragma unroll
    for (int j = 0; j < 4; j++) acc[i][j] = 0.f;

  for (int k0 = 0; k0 < K; k0 += 16) {
    __syncthreads();
    #pragma unroll
    for (int j = 0; j < 4; j++) {
      int idx = t + 256 * j;          // 0..1023
      int r = idx >> 4, kk = idx & 15;
      As[kk][r] = b2f(A[(size_t)(row0 + r) * lda + k0 + kk]);
      Bs[kk][r] = b2f(Bw[(size_t)(col0 + r) * ldb + k0 + kk]);
    }
    __syncthreads();
    #pragma unroll
    for (int kk = 0; kk < 16; kk++) {
      float4 av = *(const float4*)&As[kk][tr * 4];
      float4 bv = *(const float4*)&Bs[kk][tc * 4];
      float aa[4] = {av.x, av.y, av.z, av.w};
      float bb[4] = {bv.x, bv.y, bv.z, bv.w};
      #pragma unroll
      for (int i = 0; i < 4; i++)
        #pragma unroll
        for (int j = 0; j < 4; j++)
          acc[i][j] += aa[i] * bb[j];
    }
  }
  #pragma unroll
  for (int i = 0; i < 4; i++) {
    int rowb = row0 + tr * 4 + i;
    #pragma unroll
    for (int j = 0; j < 4; j++) {
      int colb = col0 + tc * 4 + j;
      float v = acc[i][j] + bias[colb];
      if (QSCALE) { if (colb < 384) v *= 0.125f; }  // fold 1/sqrt(D) into Q
      if (OUT_F32) ((float*)outp)[(size_t)rowb * ldc + colb] = v;
      else ((u16*)outp)[(size_t)rowb * ldc + colb] = f2bf(v);
    }
  }
}

// ---------------- VALU flash attention with polar bias ---------------------
// 64-thread block = one q-tile; each THREAD owns one q-row (private softmax).
// K/V read directly from qkv via broadcast uint4 loads (L2-resident).
__global__ __launch_bounds__(64) void attn_valu(
    const u16* __restrict__ qkv, const float* __restrict__ pos,
    const float* __restrict__ bcf, const float* __restrict__ ccf,
    u16* __restrict__ obuf)
{
  int blk = blockIdx.x;                 // b*96 + h*16 + qt
  int qt = blk & 15, h = (blk >> 4) % 6, b = blk / 96;
  int t = threadIdx.x;
  int qr = qt * 64 + t;

  float bc[15], cc[15];
  #pragma unroll
  for (int i = 0; i < 15; i++) { bc[i] = bcf[h * 15 + i]; cc[i] = ccf[h * 15 + i]; }

  const u16* qrow = qkv + (size_t)(b * 1024 + qr) * 1152 + h * 64;
  float q[64];
  #pragma unroll
  for (int c8 = 0; c8 < 8; c8++) {
    uint4 w = *(const uint4*)(qrow + c8 * 8);
    q[c8*8+0] = bflo(w.x); q[c8*8+1] = bfhi(w.x);
    q[c8*8+2] = bflo(w.y); q[c8*8+3] = bfhi(w.y);
    q[c8*8+4] = bflo(w.z); q[c8*8+5] = bfhi(w.z);
    q[c8*8+6] = bflo(w.w); q[c8*8+7] = bfhi(w.w);
  }
  float qx = pos[(size_t)(b * 1024 + qr) * 2 + 0];
  float qy = pos[(size_t)(b * 1024 + qr) * 2 + 1];

  float o[64];
  #pragma unroll
  for (int c = 0; c < 64; c++) o[c] = 0.f;
  float m = -1e30f, l = 0.f;

  const u16* kbase = qkv + (size_t)b * 1024 * 1152 + 384 + h * 64;
  const u16* vbase = qkv + (size_t)b * 1024 * 1152 + 768 + h * 64;
  const float* pb = pos + (size_t)b * 2048;

  for (int kk = 0; kk < 1024; kk++) {
    const uint4* kr = (const uint4*)(kbase + (size_t)kk * 1152);
    float s = 0.f;
    #pragma unroll
    for (int c8 = 0; c8 < 8; c8++) {
      uint4 w = kr[c8];
      s += q[c8*8+0]*bflo(w.x) + q[c8*8+1]*bfhi(w.x)
         + q[c8*8+2]*bflo(w.y) + q[c8*8+3]*bfhi(w.y)
         + q[c8*8+4]*bflo(w.z) + q[c8*8+5]*bfhi(w.z)
         + q[c8*8+6]*bflo(w.w) + q[c8*8+7]*bfhi(w.w);
    }
    // polar bias: cos/sin(n*theta) via angle-addition; Horner in r.
    float kx = pb[kk * 2], ky = pb[kk * 2 + 1];
    float dx = qx - kx, dy = qy - ky;
    float r2 = dx * dx + dy * dy;
    bool zz = !(r2 > 0.f);                 // diagonal: atan2(0,0)=0, r=0
    float ir = zz ? 0.f : __builtin_amdgcn_rsqf(r2);
    float rr = r2 * ir;                    // r
    float c1 = zz ? 1.f : dx * ir;         // cos(theta)
    float s1 = dy * ir;                    // sin(theta), 0 when zz
    float c2 = c1*c1 - s1*s1, s2 = 2.f*c1*s1;
    float c3 = c1*c2 - s1*s2, s3 = s1*c2 + c1*s2;
    float c4 = c2*c2 - s2*s2, s4 = 2.f*c2*s2;
    float a0 = bc[0] + bc[1]*c1 + bc[2]*c2 + bc[3]*c3 + bc[4]*c4
             + cc[1]*s1 + cc[2]*s2 + cc[3]*s3 + cc[4]*s4;
    float a1 = bc[5] + bc[6]*c1 + bc[7]*c2 + bc[8]*c3 + bc[9]*c4
             + cc[6]*s1 + cc[7]*s2 + cc[8]*s3 + cc[9]*s4;
    float a2 = bc[10] + bc[11]*c1 + bc[12]*c2 + bc[13]*c3 + bc[14]*c4
             + cc[11]*s1 + cc[12]*s2 + cc[13]*s3 + cc[14]*s4;
    s += a0 + rr * (a1 + rr * a2);

    float mn = fmaxf(m, s);
    float sc = __builtin_amdgcn_exp2f((m - mn) * 1.44269504f);
    float p  = __builtin_amdgcn_exp2f((s - mn) * 1.44269504f);
    l = l * sc + p;
    m = mn;
    const uint4* vr = (const uint4*)(vbase + (size_t)kk * 1152);
    #pragma unroll
    for (int c8 = 0; c8 < 8; c8++) {
      uint4 w = vr[c8];
      o[c8*8+0] = o[c8*8+0]*sc + p*bflo(w.x);
      o[c8*8+1] = o[c8*8+1]*sc + p*bfhi(w.x);
      o[c8*8+2] = o[c8*8+2]*sc + p*bflo(w.y);
      o[c8*8+3] = o[c8*8+3]*sc + p*bfhi(w.y);
      o[c8*8+4] = o[c8*8+4]*sc + p*bflo(w.z);
      o[c8*8+5] = o[c8*8+5]*sc + p*bfhi(w.z);
      o[c8*8+6] = o[c8*8+6]*sc + p*bflo(w.w);
      o[c8*8+7] = o[c8*8+7]*sc + p*bfhi(w.w);
    }
  }
  float inv = __builtin_amdgcn_rcpf(l);
  u16* orow = obuf + (size_t)(b * 1024 + qr) * 384 + h * 64;
  #pragma unroll
  for (int c = 0; c < 64; c++) orow[c] = f2bf(o[c] * inv);
}

// ---------------- launch ---------------------------------------------------
extern "C" void kernel_launch(void* const* d_in, const int* in_sizes, int n_in,
                              void* d_out, int out_size, void* d_ws, size_t ws_size,
                              hipStream_t stream) {
  const float* x      = (const float*)d_in[0];
  const float* pos    = (const float*)d_in[1];
  const float* w_norm = (const float*)d_in[2];
  const float* w_in   = (const float*)d_in[3];
  const float* b_in   = (const float*)d_in[4];
  const float* w_out  = (const float*)d_in[5];
  const float* b_out  = (const float*)d_in[6];
  const float* b_coef = (const float*)d_in[7];
  const float* c_coef = (const float*)d_in[8];

  char* ws = (char*)d_ws;
  // ws layout (25.1 MB):
  //   [0, 6291456)        xn (bf16 8192x384); obuf overlays it (xn dead after GEMM1)
  //   [6291456, 7176192)  winb (bf16 1152x384)
  //   [7176192, 7471104)  woutb (bf16 384x384)
  //   [7471104, 26345472) qkv (bf16 8192x1152), Q pre-scaled by 1/8
  u16* xn    = (u16*)(ws + 0);
  u16* obuf  = (u16*)(ws + 0);          // overlays xn
  u16* winb  = (u16*)(ws + 6291456);
  u16* woutb = (u16*)(ws + 7176192);
  u16* qkvb  = (u16*)(ws + 7471104);

  prep_kernel<<<2336, 256, 0, stream>>>(x, w_norm, w_in, w_out, xn, winb, woutb);
  gemm_valu<false, true><<<dim3(128, 18), 256, 0, stream>>>(
      xn, 384, winb, 384, b_in, qkvb, 1152, 384);
  attn_valu<<<768, 64, 0, stream>>>(qkvb, pos, b_coef, c_coef, obuf);
  gemm_valu<true, false><<<dim3(128, 6), 256, 0, stream>>>(
      obuf, 384, woutb, 384, b_out, (float*)d_out, 384, 384);
}

// Round 4
// 794.451 us; speedup vs baseline: 1.7646x; 1.7646x over previous
//
#include <hip/hip_runtime.h>

// Problem: B=8, L=1024, C=384, H=6, D=64, K=2(radial), N=4(angular)
// R4: MFMA GEMMs (bisect test) + 4-way key-split VALU attention.
typedef unsigned int  u32;
typedef unsigned short u16;
typedef __attribute__((ext_vector_type(8))) short short8;   // 8 bf16
typedef __attribute__((ext_vector_type(4))) float f32x4;

__device__ __forceinline__ u16 f2bf(float x) {
  union { float f; u32 u; } un; un.f = x;
  u32 r = un.u + 0x7FFFu + ((un.u >> 16) & 1u);   // RNE
  return (u16)(r >> 16);
}
__device__ __forceinline__ float bflo(u32 u) {
  union { u32 u; float f; } c; c.u = u << 16; return c.f;
}
__device__ __forceinline__ float bfhi(u32 u) {
  union { u32 u; float f; } c; c.u = u & 0xFFFF0000u; return c.f;
}
__device__ __forceinline__ float b2f(u16 v) {
  union { u32 u; float f; } c; c.u = ((u32)v) << 16; return c.f;
}
__device__ __forceinline__ f32x4 mfma_bf16(short8 a, short8 b, f32x4 c) {
  return __builtin_amdgcn_mfma_f32_16x16x32_bf16(a, b, c, 0, 0, 0);
}

// ---------------- prep: RMSNorm -> xn(bf16), convert w_in/w_out -> bf16 ----
__global__ __launch_bounds__(256) void prep_kernel(
    const float* __restrict__ x, const float* __restrict__ w_norm,
    const float* __restrict__ w_in, const float* __restrict__ w_out,
    u16* __restrict__ xn, u16* __restrict__ winb, u16* __restrict__ woutb)
{
  int blk = blockIdx.x, t = threadIdx.x;
  if (blk < 2048) {               // 8192 rows, 4 rows/block (1 per wave)
    int wv = t >> 6, lane = t & 63;
    int row = blk * 4 + wv;
    const float* xr = x + (size_t)row * 384;
    float v[6]; float ss = 0.f;
    #pragma unroll
    for (int i = 0; i < 6; i++) { v[i] = xr[lane + 64 * i]; ss += v[i] * v[i]; }
    #pragma unroll
    for (int off = 32; off > 0; off >>= 1) ss += __shfl_xor(ss, off);
    float rs = __builtin_amdgcn_rsqf(ss * (1.0f / 384.0f) + 1e-5f);
    #pragma unroll
    for (int i = 0; i < 6; i++) {
      float xv = v[i] * rs * w_norm[lane + 64 * i];
      xn[(size_t)row * 384 + lane + 64 * i] = f2bf(xv);
    }
  } else {                        // weight conversion: 442368 + 147456
    int base = (blk - 2048) * 2048 + t * 8;
    #pragma unroll
    for (int j = 0; j < 8; j++) {
      int idx = base + j;
      if (idx < 442368) winb[idx] = f2bf(w_in[idx]);
      else              woutb[idx - 442368] = f2bf(w_out[idx - 442368]);
    }
  }
}

// ---------------- MFMA GEMM: out[M,.] = A[M,K](lda)*Bw[N,K](ldb)^T + bias --
// 128x128 tile, BK=64, 4 waves (2x2), 16x16x32 bf16 MFMA, padded LDS.
template<bool OUT_F32, bool QSCALE>
__global__ __launch_bounds__(256) void gemm_kernel(
    const u16* __restrict__ A, int lda,
    const u16* __restrict__ Bw, int ldb,
    const float* __restrict__ bias, void* __restrict__ outp, int ldc, int K)
{
  __shared__ __attribute__((aligned(16))) u16 As[128 * 72];
  __shared__ __attribute__((aligned(16))) u16 Bs[128 * 72];
  int t = threadIdx.x;
  int lane = t & 63, wv = t >> 6;
  int g = lane >> 4, cl = lane & 15;
  int row0 = blockIdx.x * 128, col0 = blockIdx.y * 128;
  int wm = (wv >> 1) * 64, wn = (wv & 1) * 64;
  f32x4 acc[4][4];
  #pragma unroll
  for (int i = 0; i < 4; i++)
    #pragma unroll
    for (int j = 0; j < 4; j++) acc[i][j] = (f32x4){0.f, 0.f, 0.f, 0.f};

  for (int k0 = 0; k0 < K; k0 += 64) {
    __syncthreads();
    #pragma unroll
    for (int j = 0; j < 4; j++) {
      int i = t + 256 * j;
      int r = i >> 3, ch = i & 7;
      *(uint4*)(&As[r * 72 + ch * 8]) =
          *(const uint4*)(A + (size_t)(row0 + r) * lda + k0 + ch * 8);
      *(uint4*)(&Bs[r * 72 + ch * 8]) =
          *(const uint4*)(Bw + (size_t)(col0 + r) * ldb + k0 + ch * 8);
    }
    __syncthreads();
    #pragma unroll
    for (int kh = 0; kh < 2; kh++) {
      short8 af[4], bfr[4];
      #pragma unroll
      for (int s = 0; s < 4; s++) {
        af[s]  = *(const short8*)(&As[(wm + s * 16 + cl) * 72 + kh * 32 + g * 8]);
        bfr[s] = *(const short8*)(&Bs[(wn + s * 16 + cl) * 72 + kh * 32 + g * 8]);
      }
      #pragma unroll
      for (int i = 0; i < 4; i++)
        #pragma unroll
        for (int j = 0; j < 4; j++)
          acc[i][j] = mfma_bf16(af[i], bfr[j], acc[i][j]);
    }
  }
  // epilogue: C/D layout col=lane&15, row=4*(lane>>4)+r  [m89]
  #pragma unroll
  for (int i = 0; i < 4; i++) {
    #pragma unroll
    for (int j = 0; j < 4; j++) {
      int colb = col0 + wn + j * 16 + cl;
      float bv = bias[colb];
      #pragma unroll
      for (int r = 0; r < 4; r++) {
        int rowb = row0 + wm + i * 16 + g * 4 + r;
        float v = acc[i][j][r] + bv;
        if (QSCALE) { if (colb < 384) v *= 0.125f; }   // fold 1/sqrt(D) into Q
        if (OUT_F32) ((float*)outp)[(size_t)rowb * ldc + colb] = v;
        else ((u16*)outp)[(size_t)rowb * ldc + colb] = f2bf(v);
      }
    }
  }
}

// ---------------- VALU flash attention, 4-way key split --------------------
// Block = 256 threads: thread (kg=t>>6, ql=t&63) owns q-row (qt*64+ql) and
// keys [kg*256, kg*256+256). Private online softmax; LDS merge at the end.
__global__ __launch_bounds__(256) void attn_valu4(
    const u16* __restrict__ qkv, const float* __restrict__ pos,
    const float* __restrict__ bcf, const float* __restrict__ ccf,
    u16* __restrict__ obuf)
{
  __shared__ float osh[3][64][65];     // partial O of kg=1..3 (stride 65: 2-way banks)
  __shared__ float msh[4][64];
  __shared__ float lsh[4][64];
  int blk = blockIdx.x;                 // b*96 + h*16 + qt
  int qt = blk & 15, h = (blk >> 4) % 6, b = blk / 96;
  int t = threadIdx.x;
  int ql = t & 63, kg = t >> 6;
  int qr = qt * 64 + ql;

  float bc[15], cc[15];
  #pragma unroll
  for (int i = 0; i < 15; i++) { bc[i] = bcf[h * 15 + i]; cc[i] = ccf[h * 15 + i]; }

  const u16* qrow = qkv + (size_t)(b * 1024 + qr) * 1152 + h * 64;
  float q[64];
  #pragma unroll
  for (int c8 = 0; c8 < 8; c8++) {
    uint4 w = *(const uint4*)(qrow + c8 * 8);
    q[c8*8+0] = bflo(w.x); q[c8*8+1] = bfhi(w.x);
    q[c8*8+2] = bflo(w.y); q[c8*8+3] = bfhi(w.y);
    q[c8*8+4] = bflo(w.z); q[c8*8+5] = bfhi(w.z);
    q[c8*8+6] = bflo(w.w); q[c8*8+7] = bfhi(w.w);
  }
  float qx = pos[(size_t)(b * 1024 + qr) * 2 + 0];
  float qy = pos[(size_t)(b * 1024 + qr) * 2 + 1];

  float o[64];
  #pragma unroll
  for (int c = 0; c < 64; c++) o[c] = 0.f;
  float m = -1e30f, l = 0.f;

  const u16* kbase = qkv + (size_t)b * 1024 * 1152 + (size_t)(kg * 256) * 1152 + 384 + h * 64;
  const u16* vbase = kbase + 384;      // V slots are +384 elements from K slots
  const float* pb = pos + (size_t)b * 2048 + kg * 512;

  for (int kk = 0; kk < 256; kk++) {
    const uint4* kr = (const uint4*)(kbase + (size_t)kk * 1152);
    float s = 0.f;
    #pragma unroll
    for (int c8 = 0; c8 < 8; c8++) {
      uint4 w = kr[c8];
      s += q[c8*8+0]*bflo(w.x) + q[c8*8+1]*bfhi(w.x)
         + q[c8*8+2]*bflo(w.y) + q[c8*8+3]*bfhi(w.y)
         + q[c8*8+4]*bflo(w.z) + q[c8*8+5]*bfhi(w.z)
         + q[c8*8+6]*bflo(w.w) + q[c8*8+7]*bfhi(w.w);
    }
    // polar bias: cos/sin(n*theta) via angle-addition; Horner in r.
    float kx = pb[kk * 2], ky = pb[kk * 2 + 1];
    float dx = qx - kx, dy = qy - ky;
    float r2 = dx * dx + dy * dy;
    bool zz = !(r2 > 0.f);                 // diagonal: atan2(0,0)=0, r=0
    float ir = zz ? 0.f : __builtin_amdgcn_rsqf(r2);
    float rr = r2 * ir;                    // r
    float c1 = zz ? 1.f : dx * ir;         // cos(theta)
    float s1 = dy * ir;                    // sin(theta), 0 when zz
    float c2 = c1*c1 - s1*s1, s2 = 2.f*c1*s1;
    float c3 = c1*c2 - s1*s2, s3 = s1*c2 + c1*s2;
    float c4 = c2*c2 - s2*s2, s4 = 2.f*c2*s2;
    float a0 = bc[0] + bc[1]*c1 + bc[2]*c2 + bc[3]*c3 + bc[4]*c4
             + cc[1]*s1 + cc[2]*s2 + cc[3]*s3 + cc[4]*s4;
    float a1 = bc[5] + bc[6]*c1 + bc[7]*c2 + bc[8]*c3 + bc[9]*c4
             + cc[6]*s1 + cc[7]*s2 + cc[8]*s3 + cc[9]*s4;
    float a2 = bc[10] + bc[11]*c1 + bc[12]*c2 + bc[13]*c3 + bc[14]*c4
             + cc[11]*s1 + cc[12]*s2 + cc[13]*s3 + cc[14]*s4;
    s += a0 + rr * (a1 + rr * a2);

    float mn = fmaxf(m, s);
    float sc = __builtin_amdgcn_exp2f((m - mn) * 1.44269504f);
    float p  = __builtin_amdgcn_exp2f((s - mn) * 1.44269504f);
    l = l * sc + p;
    m = mn;
    const uint4* vr = (const uint4*)(vbase + (size_t)kk * 1152);
    #pragma unroll
    for (int c8 = 0; c8 < 8; c8++) {
      uint4 w = vr[c8];
      o[c8*8+0] = o[c8*8+0]*sc + p*bflo(w.x);
      o[c8*8+1] = o[c8*8+1]*sc + p*bfhi(w.x);
      o[c8*8+2] = o[c8*8+2]*sc + p*bflo(w.y);
      o[c8*8+3] = o[c8*8+3]*sc + p*bfhi(w.y);
      o[c8*8+4] = o[c8*8+4]*sc + p*bflo(w.z);
      o[c8*8+5] = o[c8*8+5]*sc + p*bfhi(w.z);
      o[c8*8+6] = o[c8*8+6]*sc + p*bflo(w.w);
      o[c8*8+7] = o[c8*8+7]*sc + p*bfhi(w.w);
    }
  }
  // merge the 4 key-group partials (online-softmax combine)
  msh[kg][ql] = m;
  __syncthreads();
  float M = fmaxf(fmaxf(msh[0][ql], msh[1][ql]), fmaxf(msh[2][ql], msh[3][ql]));
  float f = __builtin_amdgcn_exp2f((m - M) * 1.44269504f);
  lsh[kg][ql] = l * f;
  if (kg > 0) {
    #pragma unroll
    for (int c = 0; c < 64; c++) osh[kg - 1][ql][c] = o[c] * f;
  }
  __syncthreads();
  if (kg == 0) {
    float lt = lsh[0][ql] + lsh[1][ql] + lsh[2][ql] + lsh[3][ql];
    float inv = __builtin_amdgcn_rcpf(lt);
    u16* orow = obuf + (size_t)(b * 1024 + qr) * 384 + h * 64;
    #pragma unroll
    for (int c = 0; c < 64; c++) {
      float ot = o[c] * f + osh[0][ql][c] + osh[1][ql][c] + osh[2][ql][c];
      orow[c] = f2bf(ot * inv);
    }
  }
}

// ---------------- launch ---------------------------------------------------
extern "C" void kernel_launch(void* const* d_in, const int* in_sizes, int n_in,
                              void* d_out, int out_size, void* d_ws, size_t ws_size,
                              hipStream_t stream) {
  const float* x      = (const float*)d_in[0];
  const float* pos    = (const float*)d_in[1];
  const float* w_norm = (const float*)d_in[2];
  const float* w_in   = (const float*)d_in[3];
  const float* b_in   = (const float*)d_in[4];
  const float* w_out  = (const float*)d_in[5];
  const float* b_out  = (const float*)d_in[6];
  const float* b_coef = (const float*)d_in[7];
  const float* c_coef = (const float*)d_in[8];

  char* ws = (char*)d_ws;
  // ws layout (25.1 MB):
  //   [0, 6291456)        xn (bf16 8192x384); obuf overlays it (xn dead after GEMM1)
  //   [6291456, 7176192)  winb (bf16 1152x384)
  //   [7176192, 7471104)  woutb (bf16 384x384)
  //   [7471104, 26345472) qkv (bf16 8192x1152), Q pre-scaled by 1/8
  u16* xn    = (u16*)(ws + 0);
  u16* obuf  = (u16*)(ws + 0);          // overlays xn
  u16* winb  = (u16*)(ws + 6291456);
  u16* woutb = (u16*)(ws + 7176192);
  u16* qkvb  = (u16*)(ws + 7471104);

  prep_kernel<<<2336, 256, 0, stream>>>(x, w_norm, w_in, w_out, xn, winb, woutb);
  gemm_kernel<false, true><<<dim3(64, 9), 256, 0, stream>>>(
      xn, 384, winb, 384, b_in, qkvb, 1152, 384);
  attn_valu4<<<768, 256, 0, stream>>>(qkvb, pos, b_coef, c_coef, obuf);
  gemm_kernel<true, false><<<dim3(64, 3), 256, 0, stream>>>(
      obuf, 384, woutb, 384, b_out, (float*)d_out, 384, 384);
}